// Round 1
// baseline (251.288 us; speedup 1.0000x reference)
//
#include <hip/hip_runtime.h>
#include <hip/hip_bf16.h>

// GAT attention scores:
//   e[edge,h] = aa[h,:F]·x[row] + aa[h,F:]·x[col]   (separable projections)
//   a = segment_softmax(leakyrelu(e), by row)       (shift-invariance: no max pass)
//
// R9: attack the divergent-gather TA wall (R4-R8 law: ~40us per divergent
// instr/edge; DS path is ~30x cheaper for the same random access).
//  1. range_sum: preload the range's 256 s1 rows (4 KB) into LDS once per
//     block; per-edge row gather becomes ds_read_b128. TA-divergent count
//     in range_sum: 2 -> 1 (only the s2[col] gather remains).
//  2. bin_scatter: in-LDS counting sort per block (hist -> scan -> LDS
//     scatter -> ordered writeout). Global binned stores become runs of
//     ~20 consecutive edges per range (2-3 lines/wave vs 64), removing
//     the divergent-store unit.
//
// ws layout unchanged: s2h 800K | combh 1.6M | partial 6.4M | binned 6.4M
//                      | counts/base/rstart/rend ~0.7M  (~15.9 MB total)

constexpr int NN = 50000;
constexpr int NE = 1600000;
constexpr int F  = 32;
constexpr int H  = 8;
constexpr float ALPHA = 0.2f;
constexpr float EPS   = 1e-12f;

constexpr int RSH     = 8;
constexpr int RNODES  = 1 << RSH;                   // 256 nodes/range -> 8 KB acc
constexpr int NR      = (NN + RNODES - 1) / RNODES; // 196 ranges
constexpr int NB      = 400;                        // blocks in bin passes
constexpr int CHUNK   = NE / NB;                    // 4000 edges/block
constexpr int SC      = 4;                          // stripes in range_sum

typedef _Float16 v8h __attribute__((ext_vector_type(8)));

__global__ __launch_bounds__(256) void node_proj_kernel(
    const float* __restrict__ x, const float* __restrict__ aa,
    float* __restrict__ combh, float* __restrict__ s2h)
{
    __shared__ float aal[H * 2 * F];
    for (int i = threadIdx.x; i < H * 2 * F; i += 256) aal[i] = aa[i];
    __syncthreads();

    int n = blockIdx.x * 256 + threadIdx.x;
    if (n >= NN) return;

    const float4* xp = reinterpret_cast<const float4*>(x + (size_t)n * F);
    float4 xv[F / 4];
#pragma unroll
    for (int i = 0; i < F / 4; ++i) xv[i] = xp[i];

    float o1[H], o2[H];
#pragma unroll
    for (int h = 0; h < H; ++h) {
        const float* a1 = &aal[h * 2 * F];
        const float* a2 = a1 + F;
        float acc1 = 0.f, acc2 = 0.f;
#pragma unroll
        for (int i = 0; i < F / 4; ++i) {
            acc1 = fmaf(a1[4*i+0], xv[i].x, acc1);
            acc1 = fmaf(a1[4*i+1], xv[i].y, acc1);
            acc1 = fmaf(a1[4*i+2], xv[i].z, acc1);
            acc1 = fmaf(a1[4*i+3], xv[i].w, acc1);
            acc2 = fmaf(a2[4*i+0], xv[i].x, acc2);
            acc2 = fmaf(a2[4*i+1], xv[i].y, acc2);
            acc2 = fmaf(a2[4*i+2], xv[i].z, acc2);
            acc2 = fmaf(a2[4*i+3], xv[i].w, acc2);
        }
        o1[h] = acc1; o2[h] = acc2;
    }

    v8h s1v, s2v;
#pragma unroll
    for (int h = 0; h < H; ++h) { s1v[h] = (_Float16)o1[h]; s2v[h] = (_Float16)o2[h]; }
    reinterpret_cast<v8h*>(combh)[(size_t)n * 2] = s1v;   // lnrech slot filled later
    reinterpret_cast<v8h*>(s2h)[n] = s2v;
}

__global__ __launch_bounds__(256) void bin_count_kernel(
    const int* __restrict__ row, int* __restrict__ counts)
{
    __shared__ int cnt[NR];
    for (int i = threadIdx.x; i < NR; i += 256) cnt[i] = 0;
    __syncthreads();
    const int base = blockIdx.x * CHUNK;
    for (int i = threadIdx.x; i < CHUNK; i += 256)
        atomicAdd(&cnt[row[base + i] >> RSH], 1);
    __syncthreads();
    for (int i = threadIdx.x; i < NR; i += 256)
        counts[i * NB + blockIdx.x] = cnt[i];
}

// one block: range starts padded to 4-entry alignment + per-(range,block) bases
__global__ __launch_bounds__(256) void scan_kernel(
    const int* __restrict__ counts, int* __restrict__ block_base,
    int* __restrict__ rstart, int* __restrict__ rend)
{
    __shared__ int rs[NR + 1];
    __shared__ int tot[NR];
    const int t = threadIdx.x;
    if (t < NR) {
        const int4* c4 = reinterpret_cast<const int4*>(counts + t * NB);
        int s = 0;
        for (int b = 0; b < NB / 4; ++b) {
            int4 v = c4[b];
            s += v.x + v.y + v.z + v.w;
        }
        tot[t] = s;
    }
    __syncthreads();
    if (t == 0) {
        int run = 0;
        for (int r = 0; r < NR; ++r) {
            run = (run + 3) & ~3;          // 16B-align each range's bin
            rs[r] = run;
            run += tot[r];
        }
        rs[NR] = (run + 3) & ~3;
    }
    __syncthreads();
    if (t < NR) {
        const int4* c4 = reinterpret_cast<const int4*>(counts + t * NB);
        int4* b4 = reinterpret_cast<int4*>(block_base + t * NB);
        int run = rs[t];
        for (int b = 0; b < NB / 4; ++b) {
            int4 v = c4[b];
            int4 o;
            o.x = run; run += v.x;
            o.y = run; run += v.y;
            o.z = run; run += v.z;
            o.w = run; run += v.w;
            b4[b] = o;
        }
        rend[t] = rs[t] + tot[t];
    }
    if (t <= NR) rstart[t] = rs[t];
}

// R9: in-LDS counting sort, then ordered (coalesced-run) global writeout.
// Replaces the per-edge divergent global scatter with DS-path work.
__global__ __launch_bounds__(256) void bin_scatter_kernel(
    const int* __restrict__ row, const int* __restrict__ col,
    const int* __restrict__ block_base, const int* __restrict__ rstart,
    const int* __restrict__ rend, unsigned* __restrict__ binned)
{
    // block 0 fills alignment pads with sentinels (ws is 0xAA-poisoned!)
    if (blockIdx.x == 0) {
        for (int r = threadIdx.x; r < NR; r += 256) {
            int p0 = rend[r], p1 = rstart[r + 1];
            for (int p = p0; p < p1; ++p) binned[p] = 0xFFFFFFFFu;
        }
    }

    __shared__ unsigned vals[CHUNK];   // 16 KB: locally sorted (r<<16|c)
    __shared__ int hist[NR];
    __shared__ int lstart[NR];
    __shared__ int cursor[NR];
    __shared__ int gbase[NR];

    const int t = threadIdx.x;
    for (int i = t; i < NR; i += 256) {
        hist[i] = 0;
        gbase[i] = block_base[i * NB + blockIdx.x];
    }
    __syncthreads();

    const int base = blockIdx.x * CHUNK;
    // pass 1: histogram of ranges (LDS atomics — DS path, cheap)
    for (int i = t; i < CHUNK; i += 256)
        atomicAdd(&hist[row[base + i] >> RSH], 1);
    __syncthreads();

    // exclusive scan over 196 bins (serial on thread 0 — ~200 LDS ops)
    if (t == 0) {
        int run = 0;
        for (int r = 0; r < NR; ++r) {
            lstart[r] = run;
            cursor[r] = run;
            run += hist[r];
        }
    }
    __syncthreads();

    // pass 2: scatter into LDS at stable per-range positions
    for (int i = t; i < CHUNK; i += 256) {
        int r = row[base + i], c = col[base + i];
        int pos = atomicAdd(&cursor[r >> RSH], 1);
        vals[pos] = ((unsigned)r << 16) | (unsigned)c;   // both < 65536
    }
    __syncthreads();

    // writeout: sorted order -> global stores are runs of same-range edges
    // (consecutive addresses), ~2-3 cache lines per wave instead of 64.
    for (int j = t; j < CHUNK; j += 256) {
        unsigned v = vals[j];
        int rg = (int)(v >> (16 + RSH));                 // range id
        binned[gbase[rg] + (j - lstart[rg])] = v;
    }
}

// grid (NR, SC), 512 thr: dense per-range LDS segment sum
// R9: s1 rows preloaded to LDS -> 1 TA-divergent gather per edge (s2 only)
__global__ __launch_bounds__(512) void range_sum_kernel(
    const unsigned* __restrict__ binned, const int* __restrict__ rstart,
    const float* __restrict__ combh, const float* __restrict__ s2h,
    float* __restrict__ partial)
{
    __shared__ float acc[RNODES * H];   // 8 KB
    __shared__ v8h  sh1[RNODES];        // 4 KB: s1 halves for this range
    const int rx = blockIdx.x;
    const int rbase = rx << RSH;
    const v8h* combv = reinterpret_cast<const v8h*>(combh);
    const v8h* s2v   = reinterpret_cast<const v8h*>(s2h);

    for (int i = threadIdx.x; i < RNODES * H; i += 512) acc[i] = 0.f;
    for (int d = threadIdx.x; d < RNODES; d += 512) {
        int n = rbase + d;
        if (n >= NN) n = NN - 1;         // guard tail range (slots unused)
        sh1[d] = combv[(size_t)n * 2];
    }
    __syncthreads();

    const int beg4 = rstart[rx] >> 2, end4 = rstart[rx + 1] >> 2;  // aligned
    const uint4* b4 = reinterpret_cast<const uint4*>(binned);

    for (int i = beg4 + blockIdx.y * 512 + threadIdx.x; i < end4; i += SC * 512) {
        uint4 q = b4[i];
        unsigned qq[4] = {q.x, q.y, q.z, q.w};
        unsigned dd[4]; bool ok[4];
        float va[4][H];
#pragma unroll
        for (int k = 0; k < 4; ++k) {                 // gather phase
            unsigned v = qq[k];
            unsigned r = v >> 16;
            unsigned d = r - (unsigned)rbase;
            ok[k] = d < (unsigned)RNODES;             // sentinel/poison rejected
            dd[k] = d;
            unsigned dcl = ok[k] ? d : 0u;
            unsigned c   = ok[k] ? (v & 0xFFFFu) : 0u;
            v8h a = sh1[dcl];                         // DS path (was TA gather)
            v8h b = s2v[c];                           // the one TA gather left
#pragma unroll
            for (int h = 0; h < H; ++h)
                va[k][h] = (float)a[h] + (float)b[h];
        }
#pragma unroll
        for (int k = 0; k < 4; ++k) {                 // compute + LDS-atomic phase
            if (!ok[k]) continue;
            unsigned d = dd[k];
            float* ap = &acc[d << 3];
#pragma unroll
            for (int h = 0; h < H; ++h) {
                float t = va[k][h];
                t = fmaxf(t, ALPHA * t);
                atomicAdd(ap + ((h + d) & 7), __expf(t));   // swizzled banks
            }
        }
    }
    __syncthreads();

    const int cnt = min(RNODES, NN - rbase);
    float* outp = partial + ((size_t)blockIdx.y * NN + rbase) * H;
    for (int j = threadIdx.x; j < cnt * H; j += 512) {
        int d = j >> 3, h = j & 7;
        outp[j] = acc[(d << 3) + ((h + d) & 7)];       // unswizzle
    }
}

// per-node: fold stripe partials, store lnrec = -log(sum+eps) as fp16
__global__ __launch_bounds__(256) void node_final_kernel(
    const float* __restrict__ partial, float* __restrict__ combh)
{
    int n = blockIdx.x * 256 + threadIdx.x;
    if (n >= NN) return;
    const float4* p4 = reinterpret_cast<const float4*>(partial);
    float4 lo = p4[(size_t)n * 2], hi = p4[(size_t)n * 2 + 1];
#pragma unroll
    for (int s = 1; s < SC; ++s) {
        float4 a = p4[(size_t)s * (NN * 2) + n * 2];
        float4 b = p4[(size_t)s * (NN * 2) + n * 2 + 1];
        lo.x += a.x; lo.y += a.y; lo.z += a.z; lo.w += a.w;
        hi.x += b.x; hi.y += b.y; hi.z += b.z; hi.w += b.w;
    }
    float s8[8] = {lo.x, lo.y, lo.z, lo.w, hi.x, hi.y, hi.z, hi.w};
    v8h lnh;
#pragma unroll
    for (int h = 0; h < H; ++h) lnh[h] = (_Float16)(-__logf(s8[h] + EPS));
    reinterpret_cast<v8h*>(combh)[(size_t)n * 2 + 1] = lnh;
}

// 4 edges/thread; 3 divergent gather instrs per edge; coalesced out stores
__global__ __launch_bounds__(256) void edge_out_kernel(
    const int* __restrict__ row, const int* __restrict__ col,
    const float* __restrict__ combh, const float* __restrict__ s2h,
    float* __restrict__ out)
{
    int e0 = (blockIdx.x * 256 + threadIdx.x) * 4;
    if (e0 >= NE) return;
    int4 r4 = *reinterpret_cast<const int4*>(row + e0);
    int4 c4 = *reinterpret_cast<const int4*>(col + e0);
    int rr[4] = {r4.x, r4.y, r4.z, r4.w};
    int cc[4] = {c4.x, c4.y, c4.z, c4.w};
    const v8h* combv = reinterpret_cast<const v8h*>(combh);
    const v8h* s2v   = reinterpret_cast<const v8h*>(s2h);

    float res[4][H];
#pragma unroll
    for (int k = 0; k < 4; ++k) {
        v8h a  = combv[(size_t)rr[k] * 2];
        v8h ln = combv[(size_t)rr[k] * 2 + 1];
        v8h b  = s2v[cc[k]];
#pragma unroll
        for (int h = 0; h < H; ++h) {
            float t = (float)a[h] + (float)b[h];
            t = fmaxf(t, ALPHA * t);
            res[k][h] = __expf(t + (float)ln[h]);   // == exp(leaky(t)) / (sum+eps)
        }
    }
#pragma unroll
    for (int h = 0; h < H; ++h) {
        *reinterpret_cast<float4*>(out + (size_t)h * NE + e0) =
            make_float4(res[0][h], res[1][h], res[2][h], res[3][h]);
    }
}

extern "C" void kernel_launch(void* const* d_in, const int* in_sizes, int n_in,
                              void* d_out, int out_size, void* d_ws, size_t ws_size,
                              hipStream_t stream) {
    const float* x   = (const float*)d_in[0];
    const float* aa  = (const float*)d_in[1];
    const int*   row = (const int*)d_in[2];
    const int*   col = (const int*)d_in[3];
    float* out = (float*)d_out;

    float* s2h     = (float*)d_ws;                       // NN*4 floats (fp16 x8)
    float* combh   = s2h + (size_t)NN * 4;               // NN*8 floats (fp16 x16)
    float* partial = combh + (size_t)NN * 8;             // SC * NN * H
    unsigned* binned = (unsigned*)(partial + (size_t)SC * NN * H);  // NE+1024
    int* counts     = (int*)(binned + NE + 1024);        // NR*NB
    int* block_base = counts + NR * NB;                  // NR*NB
    int* rstart     = block_base + NR * NB;              // NR+1
    int* rend       = rstart + NR + 1;                   // NR

    node_proj_kernel<<<(NN + 255) / 256, 256, 0, stream>>>(x, aa, combh, s2h);
    bin_count_kernel<<<NB, 256, 0, stream>>>(row, counts);
    scan_kernel<<<1, 256, 0, stream>>>(counts, block_base, rstart, rend);
    bin_scatter_kernel<<<NB, 256, 0, stream>>>(row, col, block_base, rstart, rend, binned);
    range_sum_kernel<<<dim3(NR, SC), 512, 0, stream>>>(binned, rstart, combh, s2h, partial);
    node_final_kernel<<<(NN + 255) / 256, 256, 0, stream>>>(partial, combh);
    edge_out_kernel<<<(NE / 4 + 255) / 256, 256, 0, stream>>>(row, col, combh, s2h, out);
}